// Round 6
// baseline (900.916 us; speedup 1.0000x reference)
//
#include <hip/hip_runtime.h>

#define NCB 4
#define M 512
#define D 32
#define L 64
#define B 1024
#define XS (NCB * D * L)  // 8192 floats per batch row

// d_out layout (float offsets), reference return order:
// z_q[1024*8192], loss[1], perplexity_sum[1], indices[1024*4*64*1],
// new_embedding[4*512*32], new_ema_count[4*512], new_ema_weight[4*512*32]
#define ZQ_OFF   0
#define LOSS_OFF 8388608
#define PERP_OFF 8388609
#define IDX_OFF  8388610
#define NEMB_OFF 8650754
#define NEC_OFF  8716290
#define NWE_OFF  8718338

// d_ws layout (float offsets)
#define WS_COUNTS 0
#define WS_DW     2048          // N*M
#define WS_SSE    67584         // N*M + N*M*D
#define WS_ESQ    67585         // np-exact e_sq, N*M floats
#define WS_FLOATS (WS_ESQ + NCB * M)

// screen-vs-np pairwise decision error bound ~1.4e-5; refine below 7x that
#define REFINE_EPS 1e-4f

// numpy pairwise_sum, n=32 exact emulation (8 accumulators + fixed tree)
#define NP_SUM32(sq, res) do {                                              \
    float r0=(sq)[0], r1=(sq)[1], r2=(sq)[2], r3=(sq)[3];                   \
    float r4=(sq)[4], r5=(sq)[5], r6=(sq)[6], r7=(sq)[7];                   \
    r0 += (sq)[8];  r1 += (sq)[9];  r2 += (sq)[10]; r3 += (sq)[11];         \
    r4 += (sq)[12]; r5 += (sq)[13]; r6 += (sq)[14]; r7 += (sq)[15];         \
    r0 += (sq)[16]; r1 += (sq)[17]; r2 += (sq)[18]; r3 += (sq)[19];         \
    r4 += (sq)[20]; r5 += (sq)[21]; r6 += (sq)[22]; r7 += (sq)[23];         \
    r0 += (sq)[24]; r1 += (sq)[25]; r2 += (sq)[26]; r3 += (sq)[27];         \
    r4 += (sq)[28]; r5 += (sq)[29]; r6 += (sq)[30]; r7 += (sq)[31];         \
    (res) = ((r0 + r1) + (r2 + r3)) + ((r4 + r5) + (r6 + r7));              \
} while (0)

// np-exact e_sq for all N*M rows -> ws[WS_ESQ..]
__global__ __launch_bounds__(256) void vq_esq(
    const float* __restrict__ emb, float* __restrict__ ws)
{
#pragma clang fp contract(off)
    const int r = blockIdx.x * 256 + threadIdx.x;   // 0..2047
    const float* ep = emb + (size_t)r * D;
    float sq[D];
#pragma unroll
    for (int d = 0; d < D; ++d) { const float e = ep[d]; sq[d] = e * e; }
    float res;
    NP_SUM32(sq, res);
    ws[WS_ESQ + r] = res;
}

__global__ __launch_bounds__(256, 4) void vq_main(
    const float* __restrict__ x, const float* __restrict__ emb,
    const float* __restrict__ esq,   // ws + WS_ESQ (read-only alias)
    float* __restrict__ out, float* __restrict__ ws)
{
#pragma clang fp contract(off)
    const int tid = threadIdx.x;
    const int lane = tid & 63;
    const int bid = blockIdx.x;
    const int n  = bid >> 8;                   // 256 blocks per codebook
    const int t  = ((bid & 255) << 8) + tid;   // 1 position per thread
    const float* __restrict__ embn = emb + n * (M * D);
    const float* __restrict__ esqn = esq + n * M;

    // ---- load x for this thread's position (coalesced: lanes = consecutive l)
    const int b = t >> 6, l = t & 63;
    float xr[D];
    {
        const float* xp = x + (size_t)b * XS + n * (D * L) + l;
#pragma unroll
        for (int d = 0; d < D; ++d) xr[d] = xp[d * L];
    }

    // ---- np-exact x_sq (pairwise-8 over x^2)
    float xsq;
    {
        float sq[D];
#pragma unroll
        for (int d = 0; d < D; ++d) sq[d] = xr[d] * xr[d];
        NP_SUM32(sq, xsq);
    }

    float best = 3.4e38f, secnd = 3.4e38f;
    int   bi = 0;

    // ---- phase 1: fma screen; codebook row via wave-uniform SCALAR loads
    // (m is uniform -> s_load_dwordx16 into SGPRs; v_fmaf takes 1 sgpr src)
    for (int m = 0; m < M; ++m) {
        const float* __restrict__ ep = embn + m * D;   // uniform address
        float a0 = 0.f, a1 = 0.f, a2 = 0.f, a3 = 0.f;  // 4 chains, round-4 order
#pragma unroll
        for (int h = 0; h < D; h += 16) {
            a0 = fmaf(ep[h+ 0], xr[h+ 0], a0); a0 = fmaf(ep[h+ 1], xr[h+ 1], a0);
            a0 = fmaf(ep[h+ 2], xr[h+ 2], a0); a0 = fmaf(ep[h+ 3], xr[h+ 3], a0);
            a1 = fmaf(ep[h+ 4], xr[h+ 4], a1); a1 = fmaf(ep[h+ 5], xr[h+ 5], a1);
            a1 = fmaf(ep[h+ 6], xr[h+ 6], a1); a1 = fmaf(ep[h+ 7], xr[h+ 7], a1);
            a2 = fmaf(ep[h+ 8], xr[h+ 8], a2); a2 = fmaf(ep[h+ 9], xr[h+ 9], a2);
            a2 = fmaf(ep[h+10], xr[h+10], a2); a2 = fmaf(ep[h+11], xr[h+11], a2);
            a3 = fmaf(ep[h+12], xr[h+12], a3); a3 = fmaf(ep[h+13], xr[h+13], a3);
            a3 = fmaf(ep[h+14], xr[h+14], a3); a3 = fmaf(ep[h+15], xr[h+15], a3);
        }
        const float s = fmaf(-2.f, ((a0 + a1) + (a2 + a3)), esqn[m]);
        const bool lt = s < best;
        secnd = lt ? best : fminf(secnd, s);
        best  = lt ? s : best;
        bi    = lt ? m : bi;
    }

    // ---- phase 2: wave-cooperative np-exact rescan of near-tie positions
    {
        unsigned long long mask = __ballot(secnd - best < REFINE_EPS);
        while (mask) {
            const int src = __ffsll(mask) - 1;
            mask &= mask - 1;
            // broadcast the flagged position's x and x_sq to all lanes
            float xb[D];
#pragma unroll
            for (int d = 0; d < D; ++d) xb[d] = __shfl(xr[d], src, 64);
            const float xsb = __shfl(xsq, src, 64);
            // each lane evaluates 8 codes with the exact-np formula
            float bs = 3.4e38f; int bm = M;
            for (int mb = 0; mb < 8; ++mb) {
                const int m = mb * 64 + lane;
                const float4* e4 = (const float4*)(embn + m * D);
                float ee[D];
#pragma unroll
                for (int q = 0; q < 8; ++q) {
                    const float4 v = e4[q];
                    ee[q*4+0] = v.x; ee[q*4+1] = v.y; ee[q*4+2] = v.z; ee[q*4+3] = v.w;
                }
                // einsum contig_two SSE3 path: 4 lanes, chained non-fused muladd
                float lnk[4];
#pragma unroll
                for (int il = 0; il < 4; ++il) {
                    float c;
                    c = xb[12+il] * ee[12+il];
                    c = xb[ 8+il] * ee[ 8+il] + c;
                    c = xb[ 4+il] * ee[ 4+il] + c;
                    c = xb[ 0+il] * ee[ 0+il] + c;
                    c = xb[28+il] * ee[28+il] + c;
                    c = xb[24+il] * ee[24+il] + c;
                    c = xb[20+il] * ee[20+il] + c;
                    c = xb[16+il] * ee[16+il] + c;
                    lnk[il] = c;
                }
                const float xe   = (lnk[0] + lnk[1]) + (lnk[2] + lnk[3]);
                const float a1v  = esqn[m] + xsb;
                const float dist = a1v - 2.f * xe;
                if (dist < bs || (dist == bs && m < bm)) { bs = dist; bm = m; }
            }
#pragma unroll
            for (int off = 32; off > 0; off >>= 1) {
                const float os = __shfl_xor(bs, off, 64);
                const int   om = __shfl_xor(bm, off, 64);
                if (os < bs || (os == bs && om < bm)) { bs = os; bm = om; }
            }
            if (lane == src) bi = bm;
        }
    }

    // ---- outputs: z_q (exact gather), indices, loss partial, scatter counts/dw
    float sse = 0.f;
    {
        const float* q = embn + bi * D;   // global gather, L2-resident 64KB table
        float* zq = out + ZQ_OFF + (size_t)b * XS + n * (D * L) + l;
#pragma unroll
        for (int d = 0; d < D; ++d) {
            const float qv = q[d];
            zq[d * L] = qv;
            const float diff = xr[d] - qv;
            sse = fmaf(diff, diff, sse);
        }
        out[IDX_OFF + ((size_t)b * NCB + n) * L + l] = (float)bi;
        unsafeAtomicAdd(&ws[WS_COUNTS + n * M + bi], 1.0f);
        float* dwp = ws + WS_DW + (size_t)(n * M + bi) * D;
#pragma unroll
        for (int d = 0; d < D; ++d) unsafeAtomicAdd(&dwp[d], xr[d]);
    }

    // ---- wave-reduce sse, one atomic per wave
#pragma unroll
    for (int off = 32; off > 0; off >>= 1) sse += __shfl_down(sse, off, 64);
    if (lane == 0) unsafeAtomicAdd(&ws[WS_SSE], sse);
}

__global__ __launch_bounds__(256) void vq_finalize(
    const float* __restrict__ ema_count, const float* __restrict__ ema_weight,
    const float* __restrict__ ws, float* __restrict__ out)
{
    const int n = blockIdx.x, tid = threadIdx.x;
    __shared__ float s_nec[M];
    __shared__ float s_red[16];

    float pre[2], tot = 0.f, ent = 0.f;
#pragma unroll
    for (int k = 0; k < 2; ++k) {
        const int m = tid + k * 256;
        const float c = ws[WS_COUNTS + n * M + m];
        pre[k] = 0.999f * ema_count[n * M + m] + 0.001f * c;
        tot += pre[k];
        const float p = c * (1.f / 65536.f);
        ent += p * logf(p + 1e-10f);
    }
#pragma unroll
    for (int off = 32; off > 0; off >>= 1) {
        tot += __shfl_down(tot, off, 64);
        ent += __shfl_down(ent, off, 64);
    }
    const int w = tid >> 6;
    if ((tid & 63) == 0) { s_red[w] = tot; s_red[8 + w] = ent; }
    __syncthreads();
    tot = s_red[0] + s_red[1] + s_red[2] + s_red[3];
    ent = s_red[8] + s_red[9] + s_red[10] + s_red[11];

    if (tid == 0) unsafeAtomicAdd(&out[PERP_OFF], expf(-ent));
    if (n == 0 && tid == 0) out[LOSS_OFF] = 0.25f * ws[WS_SSE] * (1.f / 8388608.f);

#pragma unroll
    for (int k = 0; k < 2; ++k) {
        const int m = tid + k * 256;
        const float nec = (pre[k] + 1e-5f) / (tot + M * 1e-5f) * tot;
        out[NEC_OFF + n * M + m] = nec;
        s_nec[m] = nec;
    }
    __syncthreads();

    for (int e = tid; e < M * D; e += 256) {
        const int m = e >> 5;
        const float wv = 0.999f * ema_weight[n * (M * D) + e] + 0.001f * ws[WS_DW + n * (M * D) + e];
        out[NWE_OFF + n * (M * D) + e] = wv;
        out[NEMB_OFF + n * (M * D) + e] = wv / s_nec[m];
    }
}

extern "C" void kernel_launch(void* const* d_in, const int* in_sizes, int n_in,
                              void* d_out, int out_size, void* d_ws, size_t ws_size,
                              hipStream_t stream) {
    const float* x          = (const float*)d_in[0];
    const float* embedding  = (const float*)d_in[1];
    const float* ema_count  = (const float*)d_in[2];
    const float* ema_weight = (const float*)d_in[3];
    float* out = (float*)d_out;
    float* ws  = (float*)d_ws;

    // zero the accumulators (counts+dw+sse) and the two atomic output scalars
    hipMemsetAsync(ws, 0, (WS_SSE + 1) * sizeof(float), stream);
    hipMemsetAsync((char*)d_out + (size_t)LOSS_OFF * sizeof(float), 0, 2 * sizeof(float), stream);

    vq_esq<<<dim3(NCB * M / 256), dim3(256), 0, stream>>>(embedding, ws);
    vq_main<<<dim3(1024), dim3(256), 0, stream>>>(x, embedding, ws + WS_ESQ, out, ws);
    vq_finalize<<<dim3(NCB), dim3(256), 0, stream>>>(ema_count, ema_weight, ws, out);
}

// Round 10
// 748.930 us; speedup vs baseline: 1.2029x; 1.2029x over previous
//
#include <hip/hip_runtime.h>

#define NCB 4
#define M 512
#define D 32
#define L 64
#define B 1024
#define XS (NCB * D * L)  // 8192 floats per batch row

// d_out layout (float offsets), reference return order:
// z_q[1024*8192], loss[1], perplexity_sum[1], indices[1024*4*64*1],
// new_embedding[4*512*32], new_ema_count[4*512], new_ema_weight[4*512*32]
#define ZQ_OFF   0
#define LOSS_OFF 8388608
#define PERP_OFF 8388609
#define IDX_OFF  8388610
#define NEMB_OFF 8650754
#define NEC_OFF  8716290
#define NWE_OFF  8718338

// d_ws layout (float offsets)
#define WS_SSE   0
#define WS_ESQ   1                      // np-exact e_sq, N*M floats
#define WS_DWP   (1 + NCB * M)          // dw partials: [N][8][M][D]
#define SBLK     8                      // stats blocks per codebook
#define SPOS     (65536 / SBLK)         // positions per stats block

// screen-vs-np pairwise decision error bound ~1.4e-5; refine below 7x that
#define REFINE_EPS 1e-4f

// numpy pairwise_sum, n=32 exact emulation (8 accumulators + fixed tree)
#define NP_SUM32(sq, res) do {                                              \
    float r0=(sq)[0], r1=(sq)[1], r2=(sq)[2], r3=(sq)[3];                   \
    float r4=(sq)[4], r5=(sq)[5], r6=(sq)[6], r7=(sq)[7];                   \
    r0 += (sq)[8];  r1 += (sq)[9];  r2 += (sq)[10]; r3 += (sq)[11];         \
    r4 += (sq)[12]; r5 += (sq)[13]; r6 += (sq)[14]; r7 += (sq)[15];         \
    r0 += (sq)[16]; r1 += (sq)[17]; r2 += (sq)[18]; r3 += (sq)[19];         \
    r4 += (sq)[20]; r5 += (sq)[21]; r6 += (sq)[22]; r7 += (sq)[23];         \
    r0 += (sq)[24]; r1 += (sq)[25]; r2 += (sq)[26]; r3 += (sq)[27];         \
    r4 += (sq)[28]; r5 += (sq)[29]; r6 += (sq)[30]; r7 += (sq)[31];         \
    (res) = ((r0 + r1) + (r2 + r3)) + ((r4 + r5) + (r6 + r7));              \
} while (0)

// np-exact e_sq for all N*M rows -> ws[WS_ESQ..]
__global__ __launch_bounds__(256) void vq_esq(
    const float* __restrict__ emb, float* __restrict__ ws)
{
#pragma clang fp contract(off)
    const int r = blockIdx.x * 256 + threadIdx.x;   // 0..2047
    const float* ep = emb + (size_t)r * D;
    float sq[D];
#pragma unroll
    for (int d = 0; d < D; ++d) { const float e = ep[d]; sq[d] = e * e; }
    float res;
    NP_SUM32(sq, res);
    ws[WS_ESQ + r] = res;
}

__global__ __launch_bounds__(256, 4) void vq_main(
    const float* __restrict__ x, const float* __restrict__ emb,
    const float* __restrict__ esq,   // ws + WS_ESQ (read-only alias)
    float* __restrict__ out, float* __restrict__ ws)
{
#pragma clang fp contract(off)
    const int tid = threadIdx.x;
    const int lane = tid & 63;
    const int bid = blockIdx.x;
    const int n  = bid >> 8;                   // 256 blocks per codebook
    const int t  = ((bid & 255) << 8) + tid;   // 1 position per thread
    const float* __restrict__ embn = emb + n * (M * D);
    const float* __restrict__ esqn = esq + n * M;

    // ---- load x for this thread's position (coalesced: lanes = consecutive l)
    const int b = t >> 6, l = t & 63;
    float xr[D];
    {
        const float* xp = x + (size_t)b * XS + n * (D * L) + l;
#pragma unroll
        for (int d = 0; d < D; ++d) xr[d] = xp[d * L];
    }

    // ---- np-exact x_sq (pairwise-8 over x^2)
    float xsq;
    {
        float sq[D];
#pragma unroll
        for (int d = 0; d < D; ++d) sq[d] = xr[d] * xr[d];
        NP_SUM32(sq, xsq);
    }

    float best = 3.4e38f, secnd = 3.4e38f;
    int   bi = 0;

    // ---- phase 1: fma screen; codebook row via wave-uniform SCALAR loads
    for (int m = 0; m < M; ++m) {
        const float* __restrict__ ep = embn + m * D;   // uniform address
        float a0 = 0.f, a1 = 0.f, a2 = 0.f, a3 = 0.f;  // 4 chains, round-4 order
#pragma unroll
        for (int h = 0; h < D; h += 16) {
            a0 = fmaf(ep[h+ 0], xr[h+ 0], a0); a0 = fmaf(ep[h+ 1], xr[h+ 1], a0);
            a0 = fmaf(ep[h+ 2], xr[h+ 2], a0); a0 = fmaf(ep[h+ 3], xr[h+ 3], a0);
            a1 = fmaf(ep[h+ 4], xr[h+ 4], a1); a1 = fmaf(ep[h+ 5], xr[h+ 5], a1);
            a1 = fmaf(ep[h+ 6], xr[h+ 6], a1); a1 = fmaf(ep[h+ 7], xr[h+ 7], a1);
            a2 = fmaf(ep[h+ 8], xr[h+ 8], a2); a2 = fmaf(ep[h+ 9], xr[h+ 9], a2);
            a2 = fmaf(ep[h+10], xr[h+10], a2); a2 = fmaf(ep[h+11], xr[h+11], a2);
            a3 = fmaf(ep[h+12], xr[h+12], a3); a3 = fmaf(ep[h+13], xr[h+13], a3);
            a3 = fmaf(ep[h+14], xr[h+14], a3); a3 = fmaf(ep[h+15], xr[h+15], a3);
        }
        const float s = fmaf(-2.f, ((a0 + a1) + (a2 + a3)), esqn[m]);
        const bool lt = s < best;
        secnd = lt ? best : fminf(secnd, s);
        best  = lt ? s : best;
        bi    = lt ? m : bi;
    }

    // ---- phase 2: wave-cooperative np-exact rescan of near-tie positions
    {
        unsigned long long mask = __ballot(secnd - best < REFINE_EPS);
        while (mask) {
            const int src = __ffsll(mask) - 1;
            mask &= mask - 1;
            float xb[D];
#pragma unroll
            for (int d = 0; d < D; ++d) xb[d] = __shfl(xr[d], src, 64);
            const float xsb = __shfl(xsq, src, 64);
            float bs = 3.4e38f; int bm = M;
            for (int mb = 0; mb < 8; ++mb) {
                const int m = mb * 64 + lane;
                const float4* e4 = (const float4*)(embn + m * D);
                float ee[D];
#pragma unroll
                for (int q = 0; q < 8; ++q) {
                    const float4 v = e4[q];
                    ee[q*4+0] = v.x; ee[q*4+1] = v.y; ee[q*4+2] = v.z; ee[q*4+3] = v.w;
                }
                // einsum contig_two SSE3 path: 4 lanes, chained non-fused muladd
                float lnk[4];
#pragma unroll
                for (int il = 0; il < 4; ++il) {
                    float c;
                    c = xb[12+il] * ee[12+il];
                    c = xb[ 8+il] * ee[ 8+il] + c;
                    c = xb[ 4+il] * ee[ 4+il] + c;
                    c = xb[ 0+il] * ee[ 0+il] + c;
                    c = xb[28+il] * ee[28+il] + c;
                    c = xb[24+il] * ee[24+il] + c;
                    c = xb[20+il] * ee[20+il] + c;
                    c = xb[16+il] * ee[16+il] + c;
                    lnk[il] = c;
                }
                const float xe   = (lnk[0] + lnk[1]) + (lnk[2] + lnk[3]);
                const float a1v  = esqn[m] + xsb;
                const float dist = a1v - 2.f * xe;
                if (dist < bs || (dist == bs && m < bm)) { bs = dist; bm = m; }
            }
#pragma unroll
            for (int off = 32; off > 0; off >>= 1) {
                const float os = __shfl_xor(bs, off, 64);
                const int   om = __shfl_xor(bm, off, 64);
                if (os < bs || (os == bs && om < bm)) { bs = os; bm = om; }
            }
            if (lane == src) bi = bm;
        }
    }

    // ---- outputs: z_q, indices, sse partial  (NO counts/dw atomics here)
    float sse = 0.f;
    {
        const float* q = embn + bi * D;
        float* zq = out + ZQ_OFF + (size_t)b * XS + n * (D * L) + l;
#pragma unroll
        for (int d = 0; d < D; ++d) {
            const float qv = q[d];
            zq[d * L] = qv;
            const float diff = xr[d] - qv;
            sse = fmaf(diff, diff, sse);
        }
        out[IDX_OFF + ((size_t)b * NCB + n) * L + l] = (float)bi;
    }
#pragma unroll
    for (int off = 32; off > 0; off >>= 1) sse += __shfl_down(sse, off, 64);
    if (lane == 0) unsafeAtomicAdd(&ws[WS_SSE], sse);
}

// dw accumulation: LDS f32 atomics (swizzled banks), non-atomic partial flush
__global__ __launch_bounds__(256) void vq_stats(
    const float* __restrict__ x, const float* __restrict__ out,
    float* __restrict__ ws)
{
    __shared__ float dwl[M * D];   // 64 KB, column-swizzled: [m][d ^ (m&31)]
    const int tid = threadIdx.x;
    const int blk = blockIdx.x;
    const int n = blk >> 3, seg = blk & 7;

#pragma unroll
    for (int k = 0; k < (M * D) / 256; ++k) dwl[tid + k * 256] = 0.f;
    __syncthreads();

    const int t0 = seg * SPOS;
    for (int k = 0; k < SPOS / 256; ++k) {
        const int t = t0 + k * 256 + tid;
        const int b = t >> 6, l = t & 63;
        const int m = (int)out[IDX_OFF + ((size_t)b * NCB + n) * L + l];
        const float* xp = x + (size_t)b * XS + n * (D * L) + l;
        const int base = m * D, sw = m & 31;
#pragma unroll
        for (int d = 0; d < D; ++d)
            atomicAdd(&dwl[base + (d ^ sw)], xp[d * L]);
    }
    __syncthreads();

    // flush (de-swizzle) to per-block partials, non-atomic
    float* dst = ws + WS_DWP + (size_t)(n * SBLK + seg) * (M * D);
#pragma unroll
    for (int k = 0; k < (M * D) / 256; ++k) {
        const int e = tid + k * 256;
        const int m = e >> 5, d = e & 31;
        dst[e] = dwl[(e & ~31) + (d ^ (m & 31))];
    }
}

__global__ __launch_bounds__(256) void vq_finalize(
    const float* __restrict__ ema_count, const float* __restrict__ ema_weight,
    const float* __restrict__ ws, float* __restrict__ out)
{
    const int n = blockIdx.x, tid = threadIdx.x;
    __shared__ int   s_cnt[M];
    __shared__ float s_nec[M];
    __shared__ float s_red[16];

#pragma unroll
    for (int k = 0; k < 2; ++k) s_cnt[tid + k * 256] = 0;
    __syncthreads();

    // histogram of the 65536 indices for this codebook (from out, exact ints)
    for (int k = 0; k < 65536 / 256; ++k) {
        const int t = k * 256 + tid;
        const int b = t >> 6, l = t & 63;
        const int m = (int)out[IDX_OFF + ((size_t)b * NCB + n) * L + l];
        atomicAdd(&s_cnt[m], 1);
    }
    __syncthreads();

    float pre[2], tot = 0.f, ent = 0.f;
#pragma unroll
    for (int k = 0; k < 2; ++k) {
        const int m = tid + k * 256;
        const float c = (float)s_cnt[m];
        pre[k] = 0.999f * ema_count[n * M + m] + 0.001f * c;
        tot += pre[k];
        const float p = c * (1.f / 65536.f);
        ent += p * logf(p + 1e-10f);
    }
#pragma unroll
    for (int off = 32; off > 0; off >>= 1) {
        tot += __shfl_down(tot, off, 64);
        ent += __shfl_down(ent, off, 64);
    }
    const int w = tid >> 6;
    if ((tid & 63) == 0) { s_red[w] = tot; s_red[8 + w] = ent; }
    __syncthreads();
    tot = s_red[0] + s_red[1] + s_red[2] + s_red[3];
    ent = s_red[8] + s_red[9] + s_red[10] + s_red[11];

    if (tid == 0) unsafeAtomicAdd(&out[PERP_OFF], expf(-ent));
    if (n == 0 && tid == 0) out[LOSS_OFF] = 0.25f * ws[WS_SSE] * (1.f / 8388608.f);

#pragma unroll
    for (int k = 0; k < 2; ++k) {
        const int m = tid + k * 256;
        const float nec = (pre[k] + 1e-5f) / (tot + M * 1e-5f) * tot;
        out[NEC_OFF + n * M + m] = nec;
        s_nec[m] = nec;
    }
    __syncthreads();

    // sum the 8 dw partials, then EMA weight + embedding
    for (int e = tid; e < M * D; e += 256) {
        float dwsum = 0.f;
#pragma unroll
        for (int p = 0; p < SBLK; ++p)
            dwsum += ws[WS_DWP + (size_t)(n * SBLK + p) * (M * D) + e];
        const int m = e >> 5;
        const float wv = 0.999f * ema_weight[n * (M * D) + e] + 0.001f * dwsum;
        out[NWE_OFF + n * (M * D) + e] = wv;
        out[NEMB_OFF + n * (M * D) + e] = wv / s_nec[m];
    }
}

extern "C" void kernel_launch(void* const* d_in, const int* in_sizes, int n_in,
                              void* d_out, int out_size, void* d_ws, size_t ws_size,
                              hipStream_t stream) {
    const float* x          = (const float*)d_in[0];
    const float* embedding  = (const float*)d_in[1];
    const float* ema_count  = (const float*)d_in[2];
    const float* ema_weight = (const float*)d_in[3];
    float* out = (float*)d_out;
    float* ws  = (float*)d_ws;

    // zero the sse accumulator and the two atomic output scalars
    hipMemsetAsync(ws + WS_SSE, 0, sizeof(float), stream);
    hipMemsetAsync((char*)d_out + (size_t)LOSS_OFF * sizeof(float), 0, 2 * sizeof(float), stream);

    vq_esq<<<dim3(NCB * M / 256), dim3(256), 0, stream>>>(embedding, ws);
    vq_main<<<dim3(1024), dim3(256), 0, stream>>>(x, embedding, ws + WS_ESQ, out, ws);
    vq_stats<<<dim3(NCB * SBLK), dim3(256), 0, stream>>>(x, out, ws);
    vq_finalize<<<dim3(NCB), dim3(256), 0, stream>>>(ema_count, ema_weight, ws, out);
}